// Round 8
// baseline (272.977 us; speedup 1.0000x reference)
//
#include <hip/hip_runtime.h>
#include <math.h>

#define BB 8
#define TT 1024
#define CC 768
#define NH 12
#define HD 64

typedef __attribute__((ext_vector_type(8))) _Float16 hv8;   // 8 fp16 (4 VGPRs)
typedef __attribute__((ext_vector_type(8))) short  short8;  // raw 16B
typedef __attribute__((ext_vector_type(4))) float  f32x4;

typedef __attribute__((address_space(3))) unsigned int lds_u32;
typedef __attribute__((address_space(1))) unsigned int glob_u32;

// async global->LDS, 16 B per lane; LDS dest = wave-uniform base + lane*16
__device__ __forceinline__ void gl16(const _Float16* g, _Float16* l) {
    __builtin_amdgcn_global_load_lds((const glob_u32*)g, (lds_u32*)l, 16, 0, 0);
}

// ---------------------------------------------------------------------------
// fp32 -> fp16 convert; grid.z selects x / ctx.
// ---------------------------------------------------------------------------
__global__ __launch_bounds__(256) void convert_f16x2(
    const float* __restrict__ x, const float* __restrict__ ctx,
    _Float16* __restrict__ xh, _Float16* __restrict__ ch, int n)
{
    const float* in = blockIdx.z ? ctx : x;
    _Float16* out   = blockIdx.z ? ch  : xh;
    int i = (blockIdx.x * 256 + threadIdx.x) * 8;
    if (i < n) {
        float4 v0 = *(const float4*)(in + i);
        float4 v1 = *(const float4*)(in + i + 4);
        hv8 h = { (_Float16)v0.x, (_Float16)v0.y, (_Float16)v0.z, (_Float16)v0.w,
                  (_Float16)v1.x, (_Float16)v1.y, (_Float16)v1.z, (_Float16)v1.w };
        *(hv8*)(out + i) = h;
    }
}

// ---------------------------------------------------------------------------
// All 4 weight transposes in one launch: WT[n][k] = W[k][n] * scale (fp16).
// 0.125 score scale folded into Wk (pow2 -> exact).
// ---------------------------------------------------------------------------
__global__ __launch_bounds__(256) void transpose_w4(
    const float* __restrict__ Wq, const float* __restrict__ Wk,
    const float* __restrict__ Wv, const float* __restrict__ Wo,
    _Float16* __restrict__ WqT, _Float16* __restrict__ WkT,
    _Float16* __restrict__ WvT, _Float16* __restrict__ WoT)
{
    const int z = blockIdx.z;
    const float* W = (z == 0) ? Wq : (z == 1) ? Wk : (z == 2) ? Wv : Wo;
    _Float16*   WT = (z == 0) ? WqT : (z == 1) ? WkT : (z == 2) ? WvT : WoT;
    const float scale = (z == 1) ? 0.125f : 1.0f;

    __shared__ float tile[64][65];
    const int tx = threadIdx.x & 15, ty = threadIdx.x >> 4;
    const int n0 = blockIdx.x * 64, k0 = blockIdx.y * 64;

    #pragma unroll
    for (int ii = 0; ii < 4; ++ii) {
        int k = ty + ii * 16;
        float4 v = *(const float4*)(W + (size_t)(k0 + k) * CC + n0 + tx * 4);
        tile[k][tx*4+0] = v.x; tile[k][tx*4+1] = v.y;
        tile[k][tx*4+2] = v.z; tile[k][tx*4+3] = v.w;
    }
    __syncthreads();
    #pragma unroll
    for (int ii = 0; ii < 4; ++ii) {
        int n = ty + ii * 16;
        _Float16* dst = WT + (size_t)(n0 + n) * CC + k0 + tx * 4;
        dst[0] = (_Float16)(tile[tx*4+0][n] * scale);
        dst[1] = (_Float16)(tile[tx*4+1][n] * scale);
        dst[2] = (_Float16)(tile[tx*4+2][n] * scale);
        dst[3] = (_Float16)(tile[tx*4+3][n] * scale);
    }
}

// ---------------------------------------------------------------------------
// Fused QKV GEMM (grid.z = 0/1/2 -> Q/K/V), fp16 in, global_load_lds staging
// with XOR-swizzled stride-64 LDS tiles.  z<2: fp16 out [b,h,t,d].
// z==2 (V): stride-137 LDS bounce, t-contiguous stores into [b,h,d,t].
// ---------------------------------------------------------------------------
__global__ __launch_bounds__(256) void gemm_qkv3(
    const _Float16* __restrict__ xh, const _Float16* __restrict__ ch,
    const _Float16* __restrict__ WqT, const _Float16* __restrict__ WkT,
    const _Float16* __restrict__ WvT,
    _Float16* __restrict__ Qh, _Float16* __restrict__ Kh,
    _Float16* __restrict__ Vt)
{
    const int z = blockIdx.z;
    const _Float16* A  = (z == 0) ? xh : ch;
    const _Float16* BT = (z == 0) ? WqT : (z == 1) ? WkT : WvT;

    __shared__ _Float16 smem[17536];   // sA[128*64] | sB[128*64]; V-epi: sT[128][137]
    _Float16* sA = smem;
    _Float16* sB = smem + 8192;

    const int tid  = threadIdx.x;
    const int wave = tid >> 6, lane = tid & 63;
    const int quad = lane >> 4, l16 = lane & 15;
    const int k7   = l16 & 7;
    const int m0 = blockIdx.y * 128, n0 = blockIdx.x * 128;
    const int mw = (wave & 1) * 64, nw = (wave >> 1) * 64;

    // staging: lane covers logical (row = base + lane>>3, chunk = (lane&7)^(lane>>3))
    const int row_l = lane >> 3;
    const int chk_l = (lane & 7) ^ row_l;
    const _Float16* gA[4];
    const _Float16* gB[4];
    _Float16* lA[4];
    _Float16* lB[4];
    #pragma unroll
    for (int ii = 0; ii < 4; ++ii) {
        int r0 = ii * 32 + wave * 8;
        gA[ii] = A  + (size_t)(m0 + r0 + row_l) * CC + chk_l * 8;
        gB[ii] = BT + (size_t)(n0 + r0 + row_l) * CC + chk_l * 8;
        lA[ii] = &sA[r0 * 64];
        lB[ii] = &sB[r0 * 64];
    }

    f32x4 acc[4][4];
    #pragma unroll
    for (int i = 0; i < 4; ++i)
        #pragma unroll
        for (int j = 0; j < 4; ++j) acc[i][j] = (f32x4){0.f,0.f,0.f,0.f};

    for (int kt = 0; kt < CC; kt += 64) {
        #pragma unroll
        for (int ii = 0; ii < 4; ++ii) {
            gl16(gA[ii] + kt, lA[ii]);
            gl16(gB[ii] + kt, lB[ii]);
        }
        __syncthreads();   // drains vmcnt -> staging visible
        #pragma unroll
        for (int kk = 0; kk < 2; ++kk) {
            hv8 af[4], bf[4];
            #pragma unroll
            for (int mi = 0; mi < 4; ++mi)
                af[mi] = *(const hv8*)&sA[(mw + mi*16 + l16)*64 + (((kk*4+quad) ^ k7) << 3)];
            #pragma unroll
            for (int nj = 0; nj < 4; ++nj)
                bf[nj] = *(const hv8*)&sB[(nw + nj*16 + l16)*64 + (((kk*4+quad) ^ k7) << 3)];
            #pragma unroll
            for (int mi = 0; mi < 4; ++mi)
                #pragma unroll
                for (int nj = 0; nj < 4; ++nj)
                    acc[mi][nj] = __builtin_amdgcn_mfma_f32_16x16x32_f16(
                        af[mi], bf[nj], acc[mi][nj], 0, 0, 0);
        }
        __syncthreads();
    }

    if (z < 2) {
        _Float16* Chead = (z == 0) ? Qh : Kh;
        #pragma unroll
        for (int mi = 0; mi < 4; ++mi)
            #pragma unroll
            for (int nj = 0; nj < 4; ++nj)
                #pragma unroll
                for (int r = 0; r < 4; ++r) {
                    int gm = m0 + mw + mi*16 + quad*4 + r;
                    int gn = n0 + nw + nj*16 + l16;
                    int bI = gm >> 10, tI = gm & 1023;
                    int hI = gn >> 6,  dI = gn & 63;
                    Chead[(((size_t)bI * NH + hI) * TT + tI) * HD + dI] =
                        (_Float16)acc[mi][nj][r];
                }
    } else {
        _Float16* sT = smem;   // [128][137] = 17536 halves
        #pragma unroll
        for (int mi = 0; mi < 4; ++mi)
            #pragma unroll
            for (int nj = 0; nj < 4; ++nj)
                #pragma unroll
                for (int r = 0; r < 4; ++r)
                    sT[(mw + mi*16 + quad*4 + r)*137 + nw + nj*16 + l16] =
                        (_Float16)acc[mi][nj][r];
        __syncthreads();
        #pragma unroll
        for (int ii = 0; ii < 8; ++ii) {
            int u = tid + ii * 256;
            int dloc = u >> 4;          // 0..127
            int tch  = u & 15;          // consecutive lanes -> consecutive t
            hv8 o;
            #pragma unroll
            for (int j = 0; j < 8; ++j) o[j] = sT[(tch*8 + j)*137 + dloc];
            int gn = n0 + dloc;
            int hI = gn >> 6, dI = gn & 63;
            int gm = m0 + tch * 8;
            int bI = gm >> 10, tI = gm & 1023;
            *(hv8*)(Vt + (((size_t)bI * NH + hI) * HD + dI) * TT + tI) = o;
        }
    }
}

// ---------------------------------------------------------------------------
// fp16 output GEMM with global_load_lds staging: out(fp32) = A @ BT^T + bias
// ---------------------------------------------------------------------------
__global__ __launch_bounds__(256) void gemm_out_f16(
    const _Float16* __restrict__ A, const _Float16* __restrict__ BT,
    const float* __restrict__ bias, float* __restrict__ out)
{
    __shared__ _Float16 sA[128*64];
    __shared__ _Float16 sB[128*64];

    const int tid  = threadIdx.x;
    const int wave = tid >> 6, lane = tid & 63;
    const int quad = lane >> 4, l16 = lane & 15;
    const int k7   = l16 & 7;
    const int m0 = blockIdx.y * 128, n0 = blockIdx.x * 128;
    const int mw = (wave & 1) * 64, nw = (wave >> 1) * 64;

    const int row_l = lane >> 3;
    const int chk_l = (lane & 7) ^ row_l;
    const _Float16* gA[4];
    const _Float16* gB[4];
    _Float16* lA[4];
    _Float16* lB[4];
    #pragma unroll
    for (int ii = 0; ii < 4; ++ii) {
        int r0 = ii * 32 + wave * 8;
        gA[ii] = A  + (size_t)(m0 + r0 + row_l) * CC + chk_l * 8;
        gB[ii] = BT + (size_t)(n0 + r0 + row_l) * CC + chk_l * 8;
        lA[ii] = &sA[r0 * 64];
        lB[ii] = &sB[r0 * 64];
    }

    f32x4 acc[4][4];
    #pragma unroll
    for (int i = 0; i < 4; ++i)
        #pragma unroll
        for (int j = 0; j < 4; ++j) acc[i][j] = (f32x4){0.f,0.f,0.f,0.f};

    for (int kt = 0; kt < CC; kt += 64) {
        #pragma unroll
        for (int ii = 0; ii < 4; ++ii) {
            gl16(gA[ii] + kt, lA[ii]);
            gl16(gB[ii] + kt, lB[ii]);
        }
        __syncthreads();
        #pragma unroll
        for (int kk = 0; kk < 2; ++kk) {
            hv8 af[4], bf[4];
            #pragma unroll
            for (int mi = 0; mi < 4; ++mi)
                af[mi] = *(const hv8*)&sA[(mw + mi*16 + l16)*64 + (((kk*4+quad) ^ k7) << 3)];
            #pragma unroll
            for (int nj = 0; nj < 4; ++nj)
                bf[nj] = *(const hv8*)&sB[(nw + nj*16 + l16)*64 + (((kk*4+quad) ^ k7) << 3)];
            #pragma unroll
            for (int mi = 0; mi < 4; ++mi)
                #pragma unroll
                for (int nj = 0; nj < 4; ++nj)
                    acc[mi][nj] = __builtin_amdgcn_mfma_f32_16x16x32_f16(
                        af[mi], bf[nj], acc[mi][nj], 0, 0, 0);
        }
        __syncthreads();
    }

    #pragma unroll
    for (int mi = 0; mi < 4; ++mi)
        #pragma unroll
        for (int nj = 0; nj < 4; ++nj)
            #pragma unroll
            for (int r = 0; r < 4; ++r) {
                int gm = m0 + mw + mi*16 + quad*4 + r;
                int gn = n0 + nw + nj*16 + l16;
                out[(size_t)gm * CC + gn] = acc[mi][nj][r] + bias[gn];
            }
}

// ---------------------------------------------------------------------------
// fp16 MFMA flash attention, BQ=128, global_load_lds staging, XOR-swizzled
// stride-64 LDS.  LDS exactly 40960 B -> 4 blocks/CU.  K pre-scaled by 1/8.
// V given transposed ([b,h,d,t]).
// ---------------------------------------------------------------------------
__global__ __launch_bounds__(256) void attn_mfma(
    const _Float16* __restrict__ Q, const _Float16* __restrict__ K,
    const _Float16* __restrict__ Vt, const float* __restrict__ relh,
    const float* __restrict__ relw, _Float16* __restrict__ O)
{
    __shared__ _Float16 sK [64*64];    // loop: K tile | prologue: relh window (35 rows)
    __shared__ _Float16 sVt[64*64];    // loop: Vt tile | prologue: relw rows
    __shared__ _Float16 sP [4*2048];   // per-wave [32][64] P | prologue: Q [128][64] + G
    __shared__ _Float16 sH [32*128];   // rh table [hk][qi]

    const int tid  = threadIdx.x;
    const int wave = tid >> 6, lane = tid & 63;
    const int quad = lane >> 4, l16 = lane & 15;
    const int k7   = l16 & 7;

    const int bid = blockIdx.x;
    const int qt  = bid & 7;           // 128-row q tile, 8 per head
    const int bh  = bid >> 3;
    const int h   = bh % NH;
    const int b   = bh / NH;
    const size_t hbase = ((size_t)b * NH + h) * TT * HD;

    // ---- prologue: Q tile into sP (swizzled), relh window -> sK, relw -> sVt
    #pragma unroll
    for (int ii = 0; ii < 4; ++ii) {
        int u = tid + ii * 256;        // 0..1023
        int row = u >> 3, c8 = u & 7;
        *(short8*)&sP[row*64 + ((c8 ^ (row & 7)) << 3)] =
            *(const short8*)(Q + hbase + (size_t)(qt*128 + row) * HD + c8*8);
    }
    #pragma unroll
    for (int ii = 0; ii < 2; ++ii) {
        int u = tid + ii * 256;
        if (u < 280) {                 // 35 rows x 8 chunks
            int row = u >> 3, c8 = u & 7;
            const float* src = relh + (size_t)(4*qt + row) * HD + c8*8;
            float4 v0 = *(const float4*)(src);
            float4 v1 = *(const float4*)(src + 4);
            hv8 s = { (_Float16)v0.x, (_Float16)v0.y, (_Float16)v0.z, (_Float16)v0.w,
                      (_Float16)v1.x, (_Float16)v1.y, (_Float16)v1.z, (_Float16)v1.w };
            *(hv8*)&sK[row*64 + ((c8 ^ (row & 7)) << 3)] = s;
        }
    }
    #pragma unroll
    for (int ii = 0; ii < 2; ++ii) {
        int u = tid + ii * 256;
        int row = u >> 3, c8 = u & 7;
        int sr = row < 63 ? row : 62;
        const float* src = relw + (size_t)sr * HD + c8*8;
        float4 v0 = *(const float4*)(src);
        float4 v1 = *(const float4*)(src + 4);
        hv8 s = { (_Float16)v0.x, (_Float16)v0.y, (_Float16)v0.z, (_Float16)v0.w,
                  (_Float16)v1.x, (_Float16)v1.y, (_Float16)v1.z, (_Float16)v1.w };
        *(hv8*)&sVt[row*64 + ((c8 ^ (row & 7)) << 3)] = s;
    }
    __syncthreads();

    // ---- persistent Q A-fragments (2 groups of 16 rows per wave)
    hv8 aQ0[2], aQ1[2];
    #pragma unroll
    for (int g = 0; g < 2; ++g) {
        int row = wave*32 + g*16 + l16;
        aQ0[g] = *(const hv8*)&sP[row*64 + ((quad ^ k7) << 3)];
        aQ1[g] = *(const hv8*)&sP[row*64 + (((4+quad) ^ k7) << 3)];
    }

    // ---- RH via MFMA: sH[hk][qi] = q_qi . relh[hq - hk + 31]; hq = qt*4+wave
    #pragma unroll
    for (int g = 0; g < 2; ++g)
        #pragma unroll
        for (int t = 0; t < 2; ++t) {
            int wr = wave + 31 - (t*16 + l16);       // in [wave, wave+31]
            int w7 = wr & 7;
            hv8 b0 = *(const hv8*)&sK[wr*64 + ((quad ^ w7) << 3)];
            hv8 b1 = *(const hv8*)&sK[wr*64 + (((4+quad) ^ w7) << 3)];
            f32x4 c = {0.f,0.f,0.f,0.f};
            c = __builtin_amdgcn_mfma_f32_16x16x32_f16(aQ0[g], b0, c, 0, 0, 0);
            c = __builtin_amdgcn_mfma_f32_16x16x32_f16(aQ1[g], b1, c, 0, 0, 0);
            #pragma unroll
            for (int r = 0; r < 4; ++r)
                sH[(t*16 + l16)*128 + wave*32 + g*16 + quad*4 + r] = (_Float16)c[r];
        }
    // ---- G = Q @ relw^T into own-wave sP region (same-wave: no barrier needed)
    #pragma unroll
    for (int g = 0; g < 2; ++g)
        #pragma unroll
        for (int t = 0; t < 4; ++t) {
            int vr = t*16 + l16;
            hv8 b0 = *(const hv8*)&sVt[vr*64 + ((quad ^ k7) << 3)];
            hv8 b1 = *(const hv8*)&sVt[vr*64 + (((4+quad) ^ k7) << 3)];
            f32x4 c = {0.f,0.f,0.f,0.f};
            c = __builtin_amdgcn_mfma_f32_16x16x32_f16(aQ0[g], b0, c, 0, 0, 0);
            c = __builtin_amdgcn_mfma_f32_16x16x32_f16(aQ1[g], b1, c, 0, 0, 0);
            #pragma unroll
            for (int r = 0; r < 4; ++r) {
                int row = g*16 + quad*4 + r;
                int col = t*16 + l16;
                sP[wave*2048 + row*64 + ((((col>>3) ^ (row&7)) << 3)) + (col&7)] =
                    (_Float16)c[r];
            }
        }
    // ---- gather RW bias (own wave region; lgkmcnt orders same-wave LDS)
    float rwReg[2][2][4];
    #pragma unroll
    for (int g = 0; g < 2; ++g)
        #pragma unroll
        for (int j = 0; j < 2; ++j)
            #pragma unroll
            for (int r = 0; r < 4; ++r) {
                int row = g*16 + quad*4 + r;
                int idx = row - j*16 - l16 + 31;     // 0..62
                rwReg[g][j][r] = (float)sP[wave*2048 + row*64 +
                                           (((idx>>3) ^ (row&7)) << 3) + (idx&7)];
            }
    __syncthreads();

    // ---- staging pointers for the K-loop
    const int row_l = lane >> 3;
    const int chk_l = (lane & 7) ^ row_l;
    const _Float16* gK0 = K  + hbase + (size_t)(wave*8      + row_l) * HD + chk_l*8;
    const _Float16* gK1 = K  + hbase + (size_t)(wave*8 + 32 + row_l) * HD + chk_l*8;
    const _Float16* gV0 = Vt + hbase + (size_t)(wave*8      + row_l) * TT + chk_l*8;
    const _Float16* gV1 = Vt + hbase + (size_t)(wave*8 + 32 + row_l) * TT + chk_l*8;
    _Float16* lK0 = &sK [(wave*8)*64];
    _Float16* lK1 = &sK [(wave*8 + 32)*64];
    _Float16* lV0 = &sVt[(wave*8)*64];
    _Float16* lV1 = &sVt[(wave*8 + 32)*64];

    f32x4 o[2][4];
    #pragma unroll
    for (int g = 0; g < 2; ++g)
        #pragma unroll
        for (int n = 0; n < 4; ++n) o[g][n] = (f32x4){0.f,0.f,0.f,0.f};
    float l[2][4] = {{0.f,0.f,0.f,0.f},{0.f,0.f,0.f,0.f}};

    for (int kt = 0; kt < 16; ++kt) {
        gl16(gK0 + (size_t)kt*64*HD, lK0);
        gl16(gK1 + (size_t)kt*64*HD, lK1);
        gl16(gV0 + kt*64, lV0);
        gl16(gV1 + kt*64, lV1);
        __syncthreads();

        // per-row RH bias (row-broadcast reads from transposed sH)
        float rh[2][2][4];
        #pragma unroll
        for (int g = 0; g < 2; ++g)
            #pragma unroll
            for (int t2 = 0; t2 < 2; ++t2)
                #pragma unroll
                for (int r = 0; r < 4; ++r)
                    rh[g][t2][r] = (float)sH[(kt*2 + t2)*128 + wave*32 + g*16 + quad*4 + r];

        // ---- scores + exp + pack P  (bK frags shared across both groups)
        float rs[2][4] = {{0.f,0.f,0.f,0.f},{0.f,0.f,0.f,0.f}};
        #pragma unroll
        for (int bb = 0; bb < 4; ++bb) {
            int krow = bb*16 + l16;
            hv8 bK0 = *(const hv8*)&sK[krow*64 + ((quad ^ k7) << 3)];
            hv8 bK1 = *(const hv8*)&sK[krow*64 + (((4+quad) ^ k7) << 3)];
            #pragma unroll
            for (int g = 0; g < 2; ++g) {
                f32x4 c = {0.f,0.f,0.f,0.f};
                c = __builtin_amdgcn_mfma_f32_16x16x32_f16(aQ0[g], bK0, c, 0, 0, 0);
                c = __builtin_amdgcn_mfma_f32_16x16x32_f16(aQ1[g], bK1, c, 0, 0, 0);
                #pragma unroll
                for (int r = 0; r < 4; ++r) {
                    float p = __expf(c[r] + rh[g][bb>>1][r] + rwReg[g][bb&1][r]);
                    rs[g][r] += p;
                    int prow = g*16 + quad*4 + r;
                    int pcol = bb*16 + l16;
                    sP[wave*2048 + prow*64 +
                       (((pcol>>3) ^ (prow&7)) << 3) + (pcol&7)] = (_Float16)p;
                }
            }
        }
        #pragma unroll
        for (int g = 0; g < 2; ++g)
            #pragma unroll
            for (int r = 0; r < 4; ++r) {
                float t = rs[g][r];
                t += __shfl_xor(t, 1);
                t += __shfl_xor(t, 2);
                t += __shfl_xor(t, 4);
                t += __shfl_xor(t, 8);
                l[g][r] += t;
            }

        // ---- O += P @ V  (bV frags shared across both groups)
        hv8 aP0[2], aP1[2];
        #pragma unroll
        for (int g = 0; g < 2; ++g) {
            int prow = g*16 + l16;
            aP0[g] = *(const hv8*)&sP[wave*2048 + prow*64 + ((quad ^ k7) << 3)];
            aP1[g] = *(const hv8*)&sP[wave*2048 + prow*64 + (((4+quad) ^ k7) << 3)];
        }
        #pragma unroll
        for (int n = 0; n < 4; ++n) {
            int vrow = n*16 + l16;
            hv8 bV0 = *(const hv8*)&sVt[vrow*64 + ((quad ^ k7) << 3)];
            hv8 bV1 = *(const hv8*)&sVt[vrow*64 + (((4+quad) ^ k7) << 3)];
            #pragma unroll
            for (int g = 0; g < 2; ++g) {
                o[g][n] = __builtin_amdgcn_mfma_f32_16x16x32_f16(aP0[g], bV0, o[g][n], 0, 0, 0);
                o[g][n] = __builtin_amdgcn_mfma_f32_16x16x32_f16(aP1[g], bV1, o[g][n], 0, 0, 0);
            }
        }
        __syncthreads();
    }

    // ---- finalize: /l, fp16 out into [b, t, C]
    #pragma unroll
    for (int g = 0; g < 2; ++g) {
        float inv[4];
        #pragma unroll
        for (int r = 0; r < 4; ++r) inv[r] = 1.f / l[g][r];
        #pragma unroll
        for (int n = 0; n < 4; ++n)
            #pragma unroll
            for (int r = 0; r < 4; ++r) {
                int t = qt*128 + wave*32 + g*16 + quad*4 + r;
                size_t addr = ((size_t)b * TT + t) * CC + h*HD + n*16 + l16;
                O[addr] = (_Float16)(o[g][n][r] * inv[r]);
            }
    }
}

// ---------------------------------------------------------------------------
extern "C" void kernel_launch(void* const* d_in, const int* in_sizes, int n_in,
                              void* d_out, int out_size, void* d_ws, size_t ws_size,
                              hipStream_t stream) {
    const float* x   = (const float*)d_in[0];
    const float* ctx = (const float*)d_in[1];
    const float* Wq  = (const float*)d_in[2];
    const float* Wk  = (const float*)d_in[3];
    const float* Wv  = (const float*)d_in[4];
    const float* Wo  = (const float*)d_in[5];
    const float* bo  = (const float*)d_in[6];
    const float* rh  = (const float*)d_in[7];
    const float* rw  = (const float*)d_in[8];
    float* out = (float*)d_out;

    const size_t MN = (size_t)BB * TT * CC;   // 6291456
    const size_t WN = (size_t)CC * CC;        // 589824
    _Float16* p = (_Float16*)d_ws;
    _Float16* xh  = p; p += MN;
    _Float16* ch  = p; p += MN;
    _Float16* WqT = p; p += WN;
    _Float16* WkT = p; p += WN;
    _Float16* WvT = p; p += WN;
    _Float16* WoT = p; p += WN;
    _Float16* Qh  = p; p += MN;
    _Float16* Kh  = p; p += MN;
    _Float16* VtB = p; p += MN;
    _Float16* Oh  = p; p += MN;

    dim3 blk(256);

    convert_f16x2<<<dim3(MN/2048, 1, 2), blk, 0, stream>>>(x, ctx, xh, ch, (int)MN);

    transpose_w4<<<dim3(12, 12, 4), blk, 0, stream>>>(
        Wq, Wk, Wv, Wo, WqT, WkT, WvT, WoT);

    gemm_qkv3<<<dim3(CC/128, (BB*TT)/128, 3), blk, 0, stream>>>(
        xh, ch, WqT, WkT, WvT, Qh, Kh, VtB);

    attn_mfma<<<dim3(BB*NH*(TT/128)), blk, 0, stream>>>(
        Qh, Kh, VtB, rh, rw, Oh);

    gemm_out_f16<<<dim3(CC/128, (BB*TT)/128), blk, 0, stream>>>(
        Oh, WoT, bo, out);
}